// Round 4
// baseline (4170.871 us; speedup 1.0000x reference)
//
#include <hip/hip_runtime.h>
#include <cmath>

// TimeLSTMCell B=64, S=512, E=256, H=512.
// Round 8 (from round-6 @2008us; round-7 regression reverted): TWO-STREAM
// SOFTWARE PIPELINE. Round-7 post-mortem: per-thread polls are wave-granular
// (a wave spans all 16 producers -> max anyway, plus divergent spin), and
// global-direct x-GEMM stalled the window it was meant to hide. This round
// hides sync latency ACROSS steps using batch independence:
//   * NWG=32: 2 groups x 16 WGs; each group owns 32 batches as two
//     independent 16-batch streams. Each WG alternates substeps
//     (stream0 step s, stream1 step s).
//   * A stream's flags are polled one full substep (~2000cy) after they were
//     set -> poll succeeds instantly in steady state.
//   * A stream's mirror/x loads are issued BEFORE the other stream's
//     finale + vmcnt drain -> load RT hidden under ~750cy of existing work.
//   * Exposed per-substep path: compute + finale + ONE store-drain RT.
//     (Round 6 paid ~3-4 serialized LIC RTs + convoy per step.)
// Everything else (weights-in-VGPR, frag layouts, mirror format, flag
// mechanics, LDS pitches, numerics) is round-6 verbatim. MFMA work per WG
// doubles (half the WGs) - free at 2.5% MfmaUtil.
//
// Safety: substep(r,s) publishes mirrors(r,s+1) then flag[r]=s+1 after a
// vmcnt(0) drain. Readers load only after seeing the flag. A parity buffer's
// next overwrite (r,s+3-ish) is gated on a flag the reader itself publishes
// AFTER its loads drained -> no reuse race. Polls target flags set strictly
// earlier in every WG's own sequential order -> no deadlock.
//
// MFMA 16x16x32 bf16 layouts (m89/m91/m120 verified):
//   A: m=lane&15, k=(lane>>4)*8+j   B: n=lane&15, k=(lane>>4)*8+j
//   D: n=lane&15, m=(lane>>4)*4+reg

typedef short bf16x8 __attribute__((ext_vector_type(8)));
typedef float f32x4  __attribute__((ext_vector_type(4)));

#define Bdim 64
#define Sdim 512
#define Edim 256
#define Hdim 512
#define NWG  32
#define NT   512
#define FSTR 16

// ws layout (bytes), identical to round 6. Total ~3.95 MB.
#define WS_FLAGS 0
#define WS_HMIR0 16384
#define WS_HMIR1 (WS_HMIR0 + 65536)
#define WS_CMIR0 (WS_HMIR1 + 65536)
#define WS_CMIR1 (WS_CMIR0 + 65536)
#define WS_WFRAG (WS_CMIR1 + 65536)       // 16cg*8wv*24k*64lane*8 bf16 = 3 MB
#define WS_DFRAG (WS_WFRAG + 3145728)     // 16cg*8wv*4k*64lane*8 bf16 = 512 KB

__device__ __forceinline__ unsigned ld_dev_u32(const unsigned* p) {
    return __hip_atomic_load(p, __ATOMIC_RELAXED, __HIP_MEMORY_SCOPE_AGENT);
}
__device__ __forceinline__ void st_dev_u32(unsigned* p, unsigned v) {
    __hip_atomic_store(p, v, __ATOMIC_RELAXED, __HIP_MEMORY_SCOPE_AGENT);
}
__device__ __forceinline__ unsigned long long ld_dev_u64(const unsigned long long* p) {
    return __hip_atomic_load(p, __ATOMIC_RELAXED, __HIP_MEMORY_SCOPE_AGENT);
}
__device__ __forceinline__ unsigned short f2bf(float f) {
    union { float f; unsigned u; } v; v.f = f;
    return (unsigned short)((v.u + 0x7FFFu + ((v.u >> 16) & 1u)) >> 16);  // RNE
}
__device__ __forceinline__ unsigned pack2(float lo, float hi) {
    return (unsigned)f2bf(lo) | ((unsigned)f2bf(hi) << 16);
}
__device__ __forceinline__ float fast_tanh(float x) {
    const float ax = __builtin_fabsf(x);
    const float e  = __expf(-2.0f * ax);
    const float t  = (1.0f - e) / (1.0f + e);
    return __builtin_copysignf(t, x);
}
__device__ __forceinline__ float fast_sigmoid(float x) {
    return 1.0f / (1.0f + __expf(-x));
}

// ---------------- pre-pass: pack weights, zero mirrors/flags ----------------
// (verbatim round 6 — frag layouts unchanged)
__global__ __launch_bounds__(256) void tlstm_prep(
    const float* __restrict__ Wall, const float* __restrict__ Uall,
    const float* __restrict__ Wd, unsigned char* __restrict__ ws)
{
    const int w = blockIdx.x, t = threadIdx.x;
    unsigned short* Wfrag = (unsigned short*)(ws + WS_WFRAG);
    unsigned short* Dfrag = (unsigned short*)(ws + WS_DFRAG);
    const int l = t & 63, ks = t >> 6, nn = l & 15, q = l >> 4;

    if (w < 128) {                       // gate fragments: WG = (cg, wv)
        const int cg = w >> 3, wv = w & 7;
        const int G = wv * 16 + nn, g = G >> 5, jj = G & 31;
        const int row = g * Hdim + cg * 32 + jj;
        for (int i = 0; i < 6; ++i) {
            const int kp = ks * 6 + i;   // 0..23
            const float* src = (kp < 16)
                ? Wall + (size_t)row * Hdim + kp * 32 + q * 8
                : Uall + (size_t)row * Edim + (kp - 16) * 32 + q * 8;
            unsigned* dst = (unsigned*)(Wfrag
                + (((size_t)(cg * 8 + wv) * 24 + kp) * 64 + l) * 8);
            #pragma unroll
            for (int p = 0; p < 4; ++p) dst[p] = pack2(src[2*p], src[2*p+1]);
        }
    } else if (w < 192) {                // d fragments: 64 WGs, 8 frags each
        const int u = w - 128, cg = u >> 2, q4 = u & 3;
        for (int half = 0; half < 2; ++half) {
            const int wv = q4 * 2 + half;        // 0..7
            const int i  = ks;                   // 0..3
            const int dt = wv >> 2, kd = (wv & 3) * 4 + i;
            const int row = cg * 32 + dt * 16 + nn;     // Wd output col
            const float* src = Wd + (size_t)row * Hdim + kd * 32 + q * 8;
            unsigned* dst = (unsigned*)(Dfrag
                + (((size_t)(cg * 8 + wv) * 4 + i) * 64 + l) * 8);
            #pragma unroll
            for (int p = 0; p < 4; ++p) dst[p] = pack2(src[2*p], src[2*p+1]);
        }
    } else {                             // zero flags + all 4 mirrors (278528 B)
        const int idx = (w - 192) * 256 + t;          // 0..16383
        uint4* z = (uint4*)ws;
        for (int i = idx; i < 17408; i += 16384) z[i] = make_uint4(0, 0, 0, 0);
        // mirror parity-0 zeros ARE the valid step-0 state (h=c=0).
    }
}

// ------------------------------- main kernel --------------------------------
__global__ __launch_bounds__(NT, 1) void tlstm_mfma(
    const float* __restrict__ x,       // [B,S,E] fp32
    const float* __restrict__ ts,      // [B,S]
    const float* __restrict__ Wall_b,  // [4H]
    const float* __restrict__ Uall_b,  // [4H]
    const float* __restrict__ Wd_b,    // [H]
    float* __restrict__ out,           // [B,S,H] | h_f | c_f (write-only)
    unsigned char* __restrict__ ws)
{
    __shared__ __align__(16) unsigned short h_sb[2][16 * 520];  // per stream
    __shared__ __align__(16) unsigned short c_sb[2][16 * 520];
    __shared__ __align__(16) unsigned short x_sb[2][16 * 264];
    __shared__ float Dred[2][4][256];
    __shared__ float act[4 * 512];
    __shared__ float decv[16];

    int* flags = (int*)(ws + WS_FLAGS);
    const unsigned short* Wfrag = (const unsigned short*)(ws + WS_WFRAG);
    const unsigned short* Dfrag = (const unsigned short*)(ws + WS_DFRAG);

    const int t    = threadIdx.x;
    const int bg   = blockIdx.x >> 4, cg = blockIdx.x & 15;
    const int b0   = bg * 32, j0 = cg * 32;     // group owns 32 batches
    const int w    = t >> 6, lane = t & 63, q = lane >> 4, nn = lane & 15;

    // gate-col identity (wave w owns gate-col tile w: 16 cols)
    const int G = w * 16 + nn, g = G >> 5, jj = G & 31;
    const float bias_g = Wall_b[g * Hdim + j0 + jj] + Uall_b[g * Hdim + j0 + jj];
    // finale identity: unit t -> (batch fm within stream, col fj)
    const int fm = t >> 5, fj = t & 31;
    const int fdt = fj >> 4, fn = fj & 15;
    const float bias_d = Wd_b[j0 + fj];

    // ---- weights -> registers, once (L2-hot loads; round-6 layout) ----
    bf16x8 bw[24];
    #pragma unroll
    for (int i = 0; i < 24; ++i)
        bw[i] = *(const bf16x8*)(Wfrag
            + (((size_t)(cg * 8 + w) * 24 + i) * 64 + lane) * 8);
    bf16x8 bd[4];
    #pragma unroll
    for (int i = 0; i < 4; ++i)
        bd[i] = *(const bf16x8*)(Dfrag
            + (((size_t)(cg * 8 + w) * 4 + i) * 64 + lane) * 8);

    const int srow = t >> 5, sc32 = t & 31;    // staging role: row, chunk

    // ---- prologue: stream-0 step-0 state is zeros; stage its x tile ----
    for (int i = t; i < 16 * 520; i += NT) { h_sb[0][i] = 0; c_sb[0][i] = 0; }
    {
        const float4* xp = (const float4*)(x + ((size_t)(b0 + srow) * Sdim + 0) * Edim + sc32 * 8);
        float4 v0 = xp[0], v1 = xp[1];
        *(uint4*)((unsigned*)&x_sb[0][0] + srow * 132 + sc32 * 4) =
            make_uint4(pack2(v0.x, v0.y), pack2(v0.z, v0.w),
                       pack2(v1.x, v1.y), pack2(v1.z, v1.w));
    }
    float c_reg0 = 0.0f, c_reg1 = 0.0f;        // per-thread c carry, per stream
    __syncthreads();

    for (int s = 0;; ++s) {
        #pragma unroll
        for (int r = 0; r < 2; ++r) {
            const int rb0 = b0 + r * 16;       // this substep's batch base
            const unsigned short* hb = &h_sb[r][0];
            const unsigned short* cb = &c_sb[r][0];
            const unsigned short* xb = &x_sb[r][0];

            // ---- MFMA: 24 gate k-steps (2 chains) + 4 d k-steps ----
            f32x4 acc0 = {0.f, 0.f, 0.f, 0.f}, acc1 = {0.f, 0.f, 0.f, 0.f};
            f32x4 accd = {0.f, 0.f, 0.f, 0.f};
            #pragma unroll
            for (int i = 0; i < 12; ++i) {
                bf16x8 av = *(const bf16x8*)(hb + nn * 520 + i * 32 + q * 8);
                acc0 = __builtin_amdgcn_mfma_f32_16x16x32_bf16(av, bw[i], acc0, 0, 0, 0);
            }
            #pragma unroll
            for (int i = 12; i < 24; ++i) {
                const unsigned short* asrc = (i < 16)
                    ? (hb + nn * 520 + i * 32 + q * 8)
                    : (xb + nn * 264 + (i - 16) * 32 + q * 8);
                bf16x8 av = *(const bf16x8*)asrc;
                acc1 = __builtin_amdgcn_mfma_f32_16x16x32_bf16(av, bw[i], acc1, 0, 0, 0);
            }
            #pragma unroll
            for (int i = 0; i < 4; ++i) {
                const int kd = (w & 3) * 4 + i;
                bf16x8 av = *(const bf16x8*)(cb + nn * 520 + kd * 32 + q * 8);
                accd = __builtin_amdgcn_mfma_f32_16x16x32_bf16(av, bd[i], accd, 0, 0, 0);
            }

            // ---- gate activations in-register, spill act + Dred ----
            const int dt = w >> 2;
            #pragma unroll
            for (int rr = 0; rr < 4; ++rr) {
                const int m = q * 4 + rr;
                const float sv = acc0[rr] + acc1[rr] + bias_g;
                act[g * 512 + m * 32 + jj] =
                    (g == 3) ? fast_tanh(sv) : fast_sigmoid(sv);
                Dred[dt][w & 3][m * 16 + ((nn + m) & 15)] = accd[rr];
            }
            if (t < 16)
                decv[t] = 1.0f / __logf(2.7182818284590452f
                                        + ts[(size_t)(rb0 + t) * Sdim + s]);

            // ---- poll the OTHER stream's producers (flags set one full
            //      substep ago -> instant in steady state) ----
            const int nr = 1 - r, ns = s + r;      // r=0: (1,s)  r=1: (0,s+1)
            const bool do_stage = (ns < Sdim);
            if (do_stage && t < 16) {
                const unsigned* fp = (const unsigned*)&flags[(bg * 16 + t) * FSTR + nr];
                while ((int)ld_dev_u32(fp) < ns) __builtin_amdgcn_s_sleep(1);
            }
            __syncthreads();                                   // A

            // ---- issue next-stream stage loads; they fly across finale+drain
            unsigned long long hv[4], cv[4];
            float4 xv0, xv1;
            if (do_stage) {
                const unsigned long long* hsrc =
                    (const unsigned long long*)(ws + WS_HMIR0 + (ns & 1) * 65536);
                const unsigned long long* csrc =
                    (const unsigned long long*)(ws + WS_CMIR0 + (ns & 1) * 65536);
                const size_t goff = (size_t)(b0 + nr * 16 + srow) * 128 + sc32 * 4;
                #pragma unroll
                for (int i = 0; i < 4; ++i) hv[i] = ld_dev_u64(hsrc + goff + i);
                #pragma unroll
                for (int i = 0; i < 4; ++i) cv[i] = ld_dev_u64(csrc + goff + i);
                const float4* xp = (const float4*)(x
                    + ((size_t)(b0 + nr * 16 + srow) * Sdim + ns) * Edim + sc32 * 8);
                xv0 = xp[0]; xv1 = xp[1];
            }

            // ---- finale: 512 units (16 batches x 32 cols); d-reduce folded
            {
                const int sl = fm * 16 + ((fn + fm) & 15);
                const float dsum = Dred[fdt][0][sl] + Dred[fdt][1][sl]
                                 + Dred[fdt][2][sl] + Dred[fdt][3][sl];
                const float cs1  = fast_tanh(dsum + bias_d);
                const float dec  = decv[fm];
                const float cp   = r ? c_reg1 : c_reg0;
                const float cadj = (cp - cs1) + cs1 * dec;
                const float f  = act[t];
                const float ii = act[512 + t];
                const float oo = act[1024 + t];
                const float gg = act[1536 + t];
                const float cn = f * cadj + ii * gg;
                const float hn = oo * fast_tanh(cn);
                if (r) c_reg1 = cn; else c_reg0 = cn;
                out[((size_t)(rb0 + fm) * Sdim + s) * Hdim + j0 + fj] = hn;
                const float hn1 = __shfl_down(hn, 1);
                const float cn1 = __shfl_down(cn, 1);
                if (s < Sdim - 1) {
                    if ((t & 1) == 0) {
                        unsigned* hmw = (unsigned*)(ws + WS_HMIR0 + ((s + 1) & 1) * 65536);
                        unsigned* cmw = (unsigned*)(ws + WS_CMIR0 + ((s + 1) & 1) * 65536);
                        const int didx = ((rb0 + fm) * Hdim + j0 + fj) >> 1;
                        st_dev_u32(hmw + didx, pack2(hn, hn1));
                        st_dev_u32(cmw + didx, pack2(cn, cn1));
                    }
                } else {
                    float* hf = out + (size_t)Bdim * Sdim * Hdim;
                    float* cf = hf + (size_t)Bdim * Hdim;
                    hf[(rb0 + fm) * Hdim + j0 + fj] = hn;
                    cf[(rb0 + fm) * Hdim + j0 + fj] = cn;
                }
            }

            if (s == Sdim - 1 && r == 1) return;   // stores flush at retire

            // ---- drain mirrors (and stage loads), publish flag, commit LDS
            asm volatile("s_waitcnt vmcnt(0)" ::: "memory");
            __syncthreads();                                   // C
            if (t == 0 && s < Sdim - 1)
                st_dev_u32((unsigned*)&flags[(bg * 16 + cg) * FSTR + r],
                           (unsigned)(s + 1));
            if (do_stage) {
                unsigned* hls = (unsigned*)&h_sb[nr][0] + srow * 260 + sc32 * 8;
                unsigned* cls = (unsigned*)&c_sb[nr][0] + srow * 260 + sc32 * 8;
                ((ulonglong2*)hls)[0] = make_ulonglong2(hv[0], hv[1]);
                ((ulonglong2*)hls)[1] = make_ulonglong2(hv[2], hv[3]);
                ((ulonglong2*)cls)[0] = make_ulonglong2(cv[0], cv[1]);
                ((ulonglong2*)cls)[1] = make_ulonglong2(cv[2], cv[3]);
                *(uint4*)((unsigned*)&x_sb[nr][0] + srow * 132 + sc32 * 4) =
                    make_uint4(pack2(xv0.x, xv0.y), pack2(xv0.z, xv0.w),
                               pack2(xv1.x, xv1.y), pack2(xv1.z, xv1.w));
            }
            __syncthreads();                                   // D
        }
    }
}

extern "C" void kernel_launch(void* const* d_in, const int* in_sizes, int n_in,
                              void* d_out, int out_size, void* d_ws, size_t ws_size,
                              hipStream_t stream) {
    const float* x      = (const float*)d_in[0];
    const float* ts     = (const float*)d_in[1];
    const float* Wall   = (const float*)d_in[2];
    const float* Wall_b = (const float*)d_in[3];
    const float* Uall   = (const float*)d_in[4];
    const float* Uall_b = (const float*)d_in[5];
    const float* Wd     = (const float*)d_in[6];
    const float* Wd_b   = (const float*)d_in[7];

    tlstm_prep<<<256, 256, 0, stream>>>(Wall, Uall, Wd, (unsigned char*)d_ws);
    tlstm_mfma<<<NWG, NT, 0, stream>>>(x, ts, Wall_b, Uall_b, Wd_b,
                                       (float*)d_out, (unsigned char*)d_ws);
}

// Round 6
// 2436.323 us; speedup vs baseline: 1.7120x; 1.7120x over previous
//
#include <hip/hip_runtime.h>
#include <cmath>

// TimeLSTMCell B=64, S=512, E=256, H=512.
// Round 10 (base = round-6 @2008us verified; r9's asm XCD path failed hard
// and is shelved). Safe latency cuts only — all previously-passed or purely
// structural:
//   * out[] HBM store DEFERRED past the flag publish: r6 paid an HBM write
//     ack (~900cy) inside the pre-flag drain barrier every step. Now the ack
//     overlaps the poll/stage window.
//   * WAVE-granular per-producer poll (r7's lane-granular mistake fixed):
//     wave w stages cols [64w,64w+64) = producers {2w,2w+1} ONLY, polls
//     those 2 flags (wave-uniform -> no divergent spin), then loads its
//     slice. Fast producers' 4KB slices load while stragglers finish; only
//     the straggler's own slice is serialized behind its flag. The group
//     barrier (C) joins the waves -> collectively all 16 flags observed
//     before any compute (same safety invariant as r6's all-16 poll).
//   * d-reduce folded into finale (passed in r7): one fewer barrier +
//     cs1v LDS round trip.
//   * decay table (16x512 f32 LDS, passed in r7): ts load + logf off the
//     per-step path.
// Barriers/step: 5 -> 3. Mirror format, flag mechanics, MFMA layouts,
// weights-in-VGPR, numerics: r6 verbatim (absmax path identical).
//
// Parity-reuse safety (unchanged invariant): WG j overwrites parity-P data
// for step s+2 only after its staging barrier for step s+1, which requires
// all 16 flags >= s+1; flag_i = s+1 is published only after WG i finished
// READING parity-P step-s data. No read-before-write or overwrite hazard.
//
// MFMA 16x16x32 bf16 layouts (m89/m91/m120 verified):
//   A: m=lane&15, k=(lane>>4)*8+j   B: n=lane&15, k=(lane>>4)*8+j
//   D: n=lane&15, m=(lane>>4)*4+reg

typedef short bf16x8 __attribute__((ext_vector_type(8)));
typedef float f32x4  __attribute__((ext_vector_type(4)));

#define Bdim 64
#define Sdim 512
#define Edim 256
#define Hdim 512
#define NWG  64
#define NT   512
#define FSTR 16

// ws layout (bytes), identical to round 6. Total ~3.95 MB.
#define WS_FLAGS 0
#define WS_HMIR0 16384
#define WS_HMIR1 (WS_HMIR0 + 65536)
#define WS_CMIR0 (WS_HMIR1 + 65536)
#define WS_CMIR1 (WS_CMIR0 + 65536)
#define WS_WFRAG (WS_CMIR1 + 65536)       // 16cg*8wv*24k*64lane*8 bf16 = 3 MB
#define WS_DFRAG (WS_WFRAG + 3145728)     // 16cg*8wv*4k*64lane*8 bf16 = 512 KB

__device__ __forceinline__ unsigned ld_dev_u32(const unsigned* p) {
    return __hip_atomic_load(p, __ATOMIC_RELAXED, __HIP_MEMORY_SCOPE_AGENT);
}
__device__ __forceinline__ void st_dev_u32(unsigned* p, unsigned v) {
    __hip_atomic_store(p, v, __ATOMIC_RELAXED, __HIP_MEMORY_SCOPE_AGENT);
}
__device__ __forceinline__ unsigned long long ld_dev_u64(const unsigned long long* p) {
    return __hip_atomic_load(p, __ATOMIC_RELAXED, __HIP_MEMORY_SCOPE_AGENT);
}
__device__ __forceinline__ unsigned short f2bf(float f) {
    union { float f; unsigned u; } v; v.f = f;
    return (unsigned short)((v.u + 0x7FFFu + ((v.u >> 16) & 1u)) >> 16);  // RNE
}
__device__ __forceinline__ unsigned pack2(float lo, float hi) {
    return (unsigned)f2bf(lo) | ((unsigned)f2bf(hi) << 16);
}
__device__ __forceinline__ float fast_tanh(float x) {
    const float ax = __builtin_fabsf(x);
    const float e  = __expf(-2.0f * ax);
    const float t  = (1.0f - e) / (1.0f + e);
    return __builtin_copysignf(t, x);
}
__device__ __forceinline__ float fast_sigmoid(float x) {
    return 1.0f / (1.0f + __expf(-x));
}

// ---------------- pre-pass: pack weights, zero mirrors/flags ----------------
// (verbatim round 6 — frag layouts unchanged)
__global__ __launch_bounds__(256) void tlstm_prep(
    const float* __restrict__ Wall, const float* __restrict__ Uall,
    const float* __restrict__ Wd, unsigned char* __restrict__ ws)
{
    const int w = blockIdx.x, t = threadIdx.x;
    unsigned short* Wfrag = (unsigned short*)(ws + WS_WFRAG);
    unsigned short* Dfrag = (unsigned short*)(ws + WS_DFRAG);
    const int l = t & 63, ks = t >> 6, nn = l & 15, q = l >> 4;

    if (w < 128) {                       // gate fragments: WG = (cg, wv)
        const int cg = w >> 3, wv = w & 7;
        const int G = wv * 16 + nn, g = G >> 5, jj = G & 31;
        const int row = g * Hdim + cg * 32 + jj;
        for (int i = 0; i < 6; ++i) {
            const int kp = ks * 6 + i;   // 0..23
            const float* src = (kp < 16)
                ? Wall + (size_t)row * Hdim + kp * 32 + q * 8
                : Uall + (size_t)row * Edim + (kp - 16) * 32 + q * 8;
            unsigned* dst = (unsigned*)(Wfrag
                + (((size_t)(cg * 8 + wv) * 24 + kp) * 64 + l) * 8);
            #pragma unroll
            for (int p = 0; p < 4; ++p) dst[p] = pack2(src[2*p], src[2*p+1]);
        }
    } else if (w < 192) {                // d fragments: 64 WGs, 8 frags each
        const int u = w - 128, cg = u >> 2, q4 = u & 3;
        for (int half = 0; half < 2; ++half) {
            const int wv = q4 * 2 + half;        // 0..7
            const int i  = ks;                   // 0..3
            const int dt = wv >> 2, kd = (wv & 3) * 4 + i;
            const int row = cg * 32 + dt * 16 + nn;     // Wd output col
            const float* src = Wd + (size_t)row * Hdim + kd * 32 + q * 8;
            unsigned* dst = (unsigned*)(Dfrag
                + (((size_t)(cg * 8 + wv) * 4 + i) * 64 + l) * 8);
            #pragma unroll
            for (int p = 0; p < 4; ++p) dst[p] = pack2(src[2*p], src[2*p+1]);
        }
    } else {                             // zero flags + all 4 mirrors (278528 B)
        const int idx = (w - 192) * 256 + t;          // 0..16383
        uint4* z = (uint4*)ws;
        for (int i = idx; i < 17408; i += 16384) z[i] = make_uint4(0, 0, 0, 0);
        // mirror parity-0 zeros ARE the valid step-0 state (h=c=0).
    }
}

// ------------------------------- main kernel --------------------------------
__global__ __launch_bounds__(NT, 2) void tlstm_mfma(
    const float* __restrict__ x,       // [B,S,E] fp32
    const float* __restrict__ ts,      // [B,S]
    const float* __restrict__ Wall_b,  // [4H]
    const float* __restrict__ Uall_b,  // [4H]
    const float* __restrict__ Wd_b,    // [H]
    float* __restrict__ out,           // [B,S,H] | h_f | c_f (write-only)
    unsigned char* __restrict__ ws)
{
    __shared__ __align__(16) unsigned short h_sb[16 * 520];   // bf16, row pad +8
    __shared__ __align__(16) unsigned short c_sb[16 * 520];
    __shared__ __align__(16) unsigned short x_sb[16 * 264];
    __shared__ float Dred[2][4][256];
    __shared__ float act[4 * 512];              // [gate][m*32+jj]
    __shared__ float dectab[16 * 512];          // [batch][s]

    int* flags = (int*)(ws + WS_FLAGS);
    const unsigned short* Wfrag = (const unsigned short*)(ws + WS_WFRAG);
    const unsigned short* Dfrag = (const unsigned short*)(ws + WS_DFRAG);

    const int t    = threadIdx.x;
    const int bg   = blockIdx.x >> 4, cg = blockIdx.x & 15;
    const int b0   = bg * 16, j0 = cg * 32;
    const int w    = t >> 6, lane = t & 63, q = lane >> 4, nn = lane & 15;

    // gate-col identity of this lane (wave w owns gate-col tile w: 16 cols)
    const int G = w * 16 + nn, g = G >> 5, jj = G & 31;
    const float bias_g = Wall_b[g * Hdim + j0 + jj] + Uall_b[g * Hdim + j0 + jj];
    // finale identity: unit t -> (batch fm, col fj); d-reduce folded in
    const int fm = t >> 5, fj = t & 31;
    const int fdt = fj >> 4, fn = fj & 15;
    const float bias_d = Wd_b[j0 + fj];

    // ---- weights -> registers, once (L2-hot loads; round-6 layout) ----
    bf16x8 bw[24];
    #pragma unroll
    for (int i = 0; i < 24; ++i)
        bw[i] = *(const bf16x8*)(Wfrag
            + (((size_t)(cg * 8 + w) * 24 + i) * 64 + lane) * 8);
    bf16x8 bd[4];
    #pragma unroll
    for (int i = 0; i < 4; ++i)
        bd[i] = *(const bf16x8*)(Dfrag
            + (((size_t)(cg * 8 + w) * 4 + i) * 64 + lane) * 8);

    const int srow = t >> 5, sc32 = t & 31;    // x-staging role: row, chunk

    // stage x[b0..b0+16, sx, :] -> x_sb (plain cached loads, fp32 -> bf16)
    auto stage_x = [&](int sx) {
        const float4* xp = (const float4*)(x + ((size_t)(b0 + srow) * Sdim + sx) * Edim + sc32 * 8);
        float4 v0 = xp[0], v1 = xp[1];
        *(uint4*)((unsigned*)x_sb + srow * 132 + sc32 * 4) =
            make_uint4(pack2(v0.x, v0.y), pack2(v0.z, v0.w),
                       pack2(v1.x, v1.y), pack2(v1.z, v1.w));
    };

    // h/c staging: wave w owns cols [64w, 64w+64) for all 16 rows
    //   = producers {2w, 2w+1}. Lane: row = lane&15, seg = lane>>4 (0..3),
    //   u64 cols [w*16 + seg*4, +4).
    const int mrow = lane & 15, seg = lane >> 4;
    auto stage_hc = [&](int si) {
        // wave-uniform poll of this wave's 2 producers only
        const unsigned* f0 = (const unsigned*)&flags[(bg * 16 + 2 * w) * FSTR];
        const unsigned* f1 = (const unsigned*)&flags[(bg * 16 + 2 * w + 1) * FSTR];
        while ((int)ld_dev_u32(f0) < si) __builtin_amdgcn_s_sleep(1);
        while ((int)ld_dev_u32(f1) < si) __builtin_amdgcn_s_sleep(1);
        const unsigned long long* hsrc =
            (const unsigned long long*)(ws + WS_HMIR0 + (si & 1) * 65536);
        const unsigned long long* csrc =
            (const unsigned long long*)(ws + WS_CMIR0 + (si & 1) * 65536);
        const size_t goff = (size_t)(b0 + mrow) * 128 + w * 16 + seg * 4;
        unsigned long long hv[4], cv[4];
        #pragma unroll
        for (int i = 0; i < 4; ++i) hv[i] = ld_dev_u64(hsrc + goff + i);
        #pragma unroll
        for (int i = 0; i < 4; ++i) cv[i] = ld_dev_u64(csrc + goff + i);
        unsigned* hl = (unsigned*)h_sb + mrow * 260 + (w * 16 + seg * 4) * 2;
        unsigned* cl = (unsigned*)c_sb + mrow * 260 + (w * 16 + seg * 4) * 2;
        ((ulonglong2*)hl)[0] = make_ulonglong2(hv[0], hv[1]);
        ((ulonglong2*)hl)[1] = make_ulonglong2(hv[2], hv[3]);
        ((ulonglong2*)cl)[0] = make_ulonglong2(cv[0], cv[1]);
        ((ulonglong2*)cl)[1] = make_ulonglong2(cv[2], cv[3]);
    };

    // ---- prologue: step-0 state is zeros (skip mirror read); decay table ----
    for (int i = t; i < 16 * 520; i += NT) { h_sb[i] = 0; c_sb[i] = 0; }
    for (int i = t; i < 16 * Sdim; i += NT)
        dectab[i] = 1.0f / __logf(2.7182818284590452f
                                  + ts[(size_t)(b0 + (i >> 9)) * Sdim + (i & 511)]);
    stage_x(0);
    float c_reg = 0.0f;                        // fp32 c carry for own unit
    float hn_keep = 0.0f; size_t out_idx = 0;  // deferred out store
    __syncthreads();

    for (int s = 0;; ++s) {
        // ---- MFMA: 24 gate k-steps (2 indep chains) + 4 d k-steps ----
        f32x4 acc0 = {0.f, 0.f, 0.f, 0.f}, acc1 = {0.f, 0.f, 0.f, 0.f};
        f32x4 accd = {0.f, 0.f, 0.f, 0.f};
        #pragma unroll
        for (int i = 0; i < 12; ++i) {
            bf16x8 av = *(const bf16x8*)(h_sb + nn * 520 + i * 32 + q * 8);
            acc0 = __builtin_amdgcn_mfma_f32_16x16x32_bf16(av, bw[i], acc0, 0, 0, 0);
        }
        #pragma unroll
        for (int i = 12; i < 24; ++i) {
            const unsigned short* asrc = (i < 16)
                ? (h_sb + nn * 520 + i * 32 + q * 8)
                : (x_sb + nn * 264 + (i - 16) * 32 + q * 8);
            bf16x8 av = *(const bf16x8*)asrc;
            acc1 = __builtin_amdgcn_mfma_f32_16x16x32_bf16(av, bw[i], acc1, 0, 0, 0);
        }
        #pragma unroll
        for (int i = 0; i < 4; ++i) {
            const int kd = (w & 3) * 4 + i;
            bf16x8 av = *(const bf16x8*)(c_sb + nn * 520 + kd * 32 + q * 8);
            accd = __builtin_amdgcn_mfma_f32_16x16x32_bf16(av, bd[i], accd, 0, 0, 0);
        }

        // ---- gate activations in-register, spill act + Dred ----
        const int dt = w >> 2;
        #pragma unroll
        for (int rr = 0; rr < 4; ++rr) {
            const int m = q * 4 + rr;
            const float sv = acc0[rr] + acc1[rr] + bias_g;
            act[g * 512 + m * 32 + jj] =
                (g == 3) ? fast_tanh(sv) : fast_sigmoid(sv);
            Dred[dt][w & 3][m * 16 + ((nn + m) & 15)] = accd[rr];
        }
        __syncthreads();                                   // A

        // ---- finale: 512 units; d-reduce folded; out store deferred ----
        {
            const int sl = fm * 16 + ((fn + fm) & 15);
            const float dsum = Dred[fdt][0][sl] + Dred[fdt][1][sl]
                             + Dred[fdt][2][sl] + Dred[fdt][3][sl];
            const float cs1  = fast_tanh(dsum + bias_d);
            const float dec  = dectab[fm * 512 + s];
            const float cadj = (c_reg - cs1) + cs1 * dec;
            const float f  = act[t];
            const float ii = act[512 + t];
            const float oo = act[1024 + t];
            const float gg = act[1536 + t];
            const float cn = f * cadj + ii * gg;
            const float hn = oo * fast_tanh(cn);
            c_reg = cn;
            hn_keep = hn;
            out_idx = ((size_t)(b0 + fm) * Sdim + s) * Hdim + j0 + fj;
            const float hn1 = __shfl_down(hn, 1);
            const float cn1 = __shfl_down(cn, 1);
            if (s < Sdim - 1) {
                if ((t & 1) == 0) {
                    unsigned* hmw = (unsigned*)(ws + WS_HMIR0 + ((s + 1) & 1) * 65536);
                    unsigned* cmw = (unsigned*)(ws + WS_CMIR0 + ((s + 1) & 1) * 65536);
                    const int didx = ((b0 + fm) * Hdim + j0 + fj) >> 1;
                    st_dev_u32(hmw + didx, pack2(hn, hn1));
                    st_dev_u32(cmw + didx, pack2(cn, cn1));
                }
            } else {
                out[out_idx] = hn;
                float* hf = out + (size_t)Bdim * Sdim * Hdim;
                float* cf = hf + (size_t)Bdim * Hdim;
                hf[(b0 + fm) * Hdim + j0 + fj] = hn;
                cf[(b0 + fm) * Hdim + j0 + fj] = cn;
            }
        }

        if (s == Sdim - 1) break;

        __syncthreads();   // B: implicit vmcnt(0) drains the 2KB mirror stores
        if (t == 0)
            st_dev_u32((unsigned*)&flags[(bg * 16 + cg) * FSTR],
                       (unsigned)(s + 1));
        out[out_idx] = hn_keep;   // deferred HBM store; ack overlaps staging
        stage_x(s + 1);           // cached loads, overlaps flag propagation
        stage_hc(s + 1);          // per-wave 2-producer poll + slice load
        __syncthreads();          // C: joins waves -> all 16 flags observed
    }
}

extern "C" void kernel_launch(void* const* d_in, const int* in_sizes, int n_in,
                              void* d_out, int out_size, void* d_ws, size_t ws_size,
                              hipStream_t stream) {
    const float* x      = (const float*)d_in[0];
    const float* ts     = (const float*)d_in[1];
    const float* Wall   = (const float*)d_in[2];
    const float* Wall_b = (const float*)d_in[3];
    const float* Uall   = (const float*)d_in[4];
    const float* Uall_b = (const float*)d_in[5];
    const float* Wd     = (const float*)d_in[6];
    const float* Wd_b   = (const float*)d_in[7];

    tlstm_prep<<<256, 256, 0, stream>>>(Wall, Uall, Wd, (unsigned char*)d_ws);
    tlstm_mfma<<<NWG, NT, 0, stream>>>(x, ts, Wall_b, Uall_b, Wd_b,
                                       (float*)d_out, (unsigned char*)d_ws);
}